// Round 2
// baseline (1327.261 us; speedup 1.0000x reference)
//
#include <hip/hip_runtime.h>
#include <math.h>

#define N_ATOMS 50000
#define P_PAIRS 1600000
#define TA 16
#define SCAN_THREADS 1024
#define SCAN_CHUNK 49   // 1024*49 = 50176 >= 50000

__device__ __forceinline__ float gelu_exact(float x) {
    return 0.5f * x * (1.0f + erff(x * 0.70710678118654752440f));
}

// ---------------- counting-sort pipeline (replaces fp32 atomic scatter) ----

__global__ __launch_bounds__(256) void hist_kernel(
    const int* __restrict__ idx_j, int* __restrict__ counts)
{
    int t = blockIdx.x * 256 + threadIdx.x;
    if (t < P_PAIRS) atomicAdd(counts + idx_j[t], 1);
}

__global__ __launch_bounds__(SCAN_THREADS) void scan_kernel(
    const int* __restrict__ counts,
    int* __restrict__ seg_off,
    int* __restrict__ cursor)
{
    __shared__ int s[SCAN_THREADS];
    const int t = threadIdx.x;
    const int base = t * SCAN_CHUNK;

    int sum = 0;
    #pragma unroll
    for (int i = 0; i < SCAN_CHUNK; i++) {
        int j = base + i;
        if (j < N_ATOMS) sum += counts[j];
    }
    s[t] = sum;
    __syncthreads();

    // Hillis-Steele inclusive scan over 1024 partials
    #pragma unroll
    for (int off = 1; off < SCAN_THREADS; off <<= 1) {
        int v = 0;
        if (t >= off) v = s[t - off];
        __syncthreads();
        if (t >= off) s[t] += v;
        __syncthreads();
    }

    int run = s[t] - sum;   // exclusive prefix for this chunk
    for (int i = 0; i < SCAN_CHUNK; i++) {
        int j = base + i;
        if (j < N_ATOMS) {
            seg_off[j] = run;
            cursor[j]  = run;
            run += counts[j];
        }
    }
    if (t == 0) seg_off[N_ATOMS] = P_PAIRS;
}

__global__ __launch_bounds__(256) void scatter_idx_kernel(
    const int* __restrict__ idx_j,
    int* __restrict__ cursor,
    int* __restrict__ sorted_p)
{
    int t = blockIdx.x * 256 + threadIdx.x;
    if (t < P_PAIRS) {
        int idx = idx_j[t];
        int pos = atomicAdd(cursor + idx, 1);
        sorted_p[pos] = t;
    }
}

// One wave per atom; lane = component c (c<16 -> gs, c>=16 -> gv).
__global__ __launch_bounds__(256) void reduce_kernel(
    const int* __restrict__ seg_off,
    const int* __restrict__ sorted_p,
    const float* __restrict__ gs,
    const float* __restrict__ gv,
    float* __restrict__ acc)
{
    const int wave = (blockIdx.x * 256 + threadIdx.x) >> 6;
    const int lane = threadIdx.x & 63;
    if (wave >= N_ATOMS) return;

    const int start = seg_off[wave];
    const int end   = seg_off[wave + 1];
    const int c = lane;
    const bool is_gs = (c < 16);
    const int c16 = c - 16;

    float a = 0.f;
    for (int i0 = start; i0 < end; i0 += 64) {
        const int nb = min(64, end - i0);
        int pl = (i0 + lane < end) ? sorted_p[i0 + lane] : 0;
        int j = 0;
        for (; j + 4 <= nb; j += 4) {
            int p0 = __shfl(pl, j + 0);
            int p1 = __shfl(pl, j + 1);
            int p2 = __shfl(pl, j + 2);
            int p3 = __shfl(pl, j + 3);
            float v0 = is_gs ? gs[p0 * 16 + c] : gv[p0 * 48 + c16];
            float v1 = is_gs ? gs[p1 * 16 + c] : gv[p1 * 48 + c16];
            float v2 = is_gs ? gs[p2 * 16 + c] : gv[p2 * 48 + c16];
            float v3 = is_gs ? gs[p3 * 16 + c] : gv[p3 * 48 + c16];
            a += v0; a += v1; a += v2; a += v3;
        }
        for (; j < nb; j++) {
            int p = __shfl(pl, j);
            a += is_gs ? gs[p * 16 + c] : gv[p * 48 + c16];
        }
    }
    acc[(size_t)wave * 64 + lane] = a;
}

// ---------------- fused per-atom kernel (unchanged from R1) ----------------

__global__ __launch_bounds__(256, 2) void fused_atom_kernel(
    const float* __restrict__ emb,
    const float* __restrict__ qch,
    const float* __restrict__ acc,
    const float* __restrict__ agh,   // (128,16,32) -> [a*512 + g*32 + h]
    const float* __restrict__ W_gf,  // (16,128)
    const float* __restrict__ W1, const float* __restrict__ b1,   // (320,256)
    const float* __restrict__ W2, const float* __restrict__ b2,   // (256,128)
    const float* __restrict__ W3, const float* __restrict__ b3,   // (128,130)
    float* __restrict__ out)
{
    __shared__ __align__(16) float s_bufA[16 * 256];
    __shared__ __align__(16) float s_bufB[16 * 512];
    __shared__ __align__(16) float s_msgT[320 * 16];   // [k][atom]
    __shared__ __align__(16) float s_gs[16 * 16];      // [atom][g]
    __shared__ __align__(16) float s_gv[16 * 48];      // [atom][d*16+g]
    __shared__ __align__(16) float s_q[16];

    const int tid = threadIdx.x;
    const int n0 = blockIdx.x * TA;

    float* s_embT = s_bufA;   // [a][atom]
    float* s_U    = s_bufB;   // [atom][gh]
    float* s_h1T  = s_bufA;   // [k][atom]
    float* s_h2T  = s_bufB;   // [k][atom]

    #pragma unroll
    for (int i = 0; i < 2; i++) {
        int ii = tid + i * 256;
        int atom = ii >> 5;
        int a4 = (ii & 31) * 4;
        float4 v = *(const float4*)(emb + (size_t)(n0 + atom) * 128 + a4);
        s_embT[(a4 + 0) * 16 + atom] = v.x;
        s_embT[(a4 + 1) * 16 + atom] = v.y;
        s_embT[(a4 + 2) * 16 + atom] = v.z;
        s_embT[(a4 + 3) * 16 + atom] = v.w;
    }
    #pragma unroll
    for (int i = 0; i < 4; i++) {
        int ii = tid + i * 256;
        int atom = ii >> 6, c = ii & 63;
        float v = acc[(size_t)(n0 + atom) * 64 + c];
        if (c < 16) s_gs[atom * 16 + c] = v;
        else        s_gv[atom * 48 + (c - 16)] = v;
    }
    if (tid < 16) s_q[tid] = qch[n0 + tid];
    __syncthreads();

    // U[atom][gh] = sum_a emb[atom][a] * agh[a][gh]
    {
        const int gh4  = (tid & 127) * 4;
        const int half = tid >> 7;
        float u[32];
        #pragma unroll
        for (int i = 0; i < 32; i++) u[i] = 0.f;
        #pragma unroll 4
        for (int a = 0; a < 128; a++) {
            float4 w  = *(const float4*)(agh + a * 512 + gh4);
            float4 e0 = *(const float4*)(s_embT + a * 16 + half * 8);
            float4 e1 = *(const float4*)(s_embT + a * 16 + half * 8 + 4);
            float wv[4] = {w.x, w.y, w.z, w.w};
            float ev[8] = {e0.x, e0.y, e0.z, e0.w, e1.x, e1.y, e1.z, e1.w};
            #pragma unroll
            for (int j = 0; j < 4; j++)
                #pragma unroll
                for (int m = 0; m < 8; m++)
                    u[j * 8 + m] += wv[j] * ev[m];
        }
        #pragma unroll
        for (int m = 0; m < 8; m++) {
            int atom = half * 8 + m;
            float4 v = {u[0 * 8 + m], u[1 * 8 + m], u[2 * 8 + m], u[3 * 8 + m]};
            *(float4*)(s_U + atom * 512 + gh4) = v;
        }
    }
    __syncthreads();

    // avf + safe_norm -> msg rows [128,160) ; zero rows [288,320)
    #pragma unroll
    for (int it = 0; it < 2; it++) {
        int i = tid + it * 256;
        int atom = i >> 5, h = i & 31;
        float v0 = 0.f, v1 = 0.f, v2 = 0.f;
        #pragma unroll
        for (int g = 0; g < 16; g++) {
            float uv = s_U[atom * 512 + g * 32 + h];
            v0 += uv * s_gv[atom * 48 + g];
            v1 += uv * s_gv[atom * 48 + 16 + g];
            v2 += uv * s_gv[atom * 48 + 32 + g];
        }
        float sq = v0 * v0 + v1 * v1 + v2 * v2;
        float nrm = (sq > 0.f) ? sqrtf(sq) : 0.f;
        s_msgT[(128 + h) * 16 + atom] = nrm;
        s_msgT[(288 + h) * 16 + atom] = 0.f;
    }

    // mapped = GS_sum @ W_gf ; rad_emb rows [0,128) ; rad_q rows [160,288)
    {
        const int f = tid & 127;
        const int half = tid >> 7;
        float mp[8];
        #pragma unroll
        for (int a = 0; a < 8; a++) mp[a] = 0.f;
        #pragma unroll
        for (int g = 0; g < 16; g++) {
            float w = W_gf[g * 128 + f];
            #pragma unroll
            for (int a = 0; a < 8; a++)
                mp[a] += s_gs[(half * 8 + a) * 16 + g] * w;
        }
        #pragma unroll
        for (int a = 0; a < 8; a++) {
            int atom = half * 8 + a;
            float e = s_embT[f * 16 + atom];
            s_msgT[f * 16 + atom]         = e * mp[a];
            s_msgT[(160 + f) * 16 + atom] = s_q[atom] * mp[a];
        }
    }
    __syncthreads();

    // MLP layer 1: h1 = gelu(msg @ W1 + b1), 320 -> 256
    {
        const int o4 = (tid & 63) * 4;
        const int q4 = (tid >> 6) * 4;
        float acc1[16];
        #pragma unroll
        for (int i = 0; i < 16; i++) acc1[i] = 0.f;
        #pragma unroll 4
        for (int k = 0; k < 320; k++) {
            float4 w  = *(const float4*)(W1 + k * 256 + o4);
            float4 mm = *(const float4*)(s_msgT + k * 16 + q4);
            float wv[4] = {w.x, w.y, w.z, w.w};
            float mv[4] = {mm.x, mm.y, mm.z, mm.w};
            #pragma unroll
            for (int j = 0; j < 4; j++)
                #pragma unroll
                for (int m = 0; m < 4; m++)
                    acc1[j * 4 + m] += wv[j] * mv[m];
        }
        #pragma unroll
        for (int j = 0; j < 4; j++) {
            int o = o4 + j;
            float bb = b1[o];
            float4 v;
            v.x = gelu_exact(acc1[j * 4 + 0] + bb);
            v.y = gelu_exact(acc1[j * 4 + 1] + bb);
            v.z = gelu_exact(acc1[j * 4 + 2] + bb);
            v.w = gelu_exact(acc1[j * 4 + 3] + bb);
            *(float4*)(s_h1T + o * 16 + q4) = v;
        }
    }
    __syncthreads();

    // MLP layer 2: h2 = gelu(h1 @ W2 + b2), 256 -> 128
    {
        const int o4 = (tid & 31) * 4;
        const int a2 = (tid >> 5) * 2;
        float acc2[8];
        #pragma unroll
        for (int i = 0; i < 8; i++) acc2[i] = 0.f;
        #pragma unroll 4
        for (int k = 0; k < 256; k++) {
            float4 w  = *(const float4*)(W2 + k * 128 + o4);
            float2 hh = *(const float2*)(s_h1T + k * 16 + a2);
            float wv[4] = {w.x, w.y, w.z, w.w};
            float hv[2] = {hh.x, hh.y};
            #pragma unroll
            for (int j = 0; j < 4; j++)
                #pragma unroll
                for (int m = 0; m < 2; m++)
                    acc2[j * 2 + m] += wv[j] * hv[m];
        }
        #pragma unroll
        for (int j = 0; j < 4; j++) {
            int o = o4 + j;
            float bb = b2[o];
            float2 v;
            v.x = gelu_exact(acc2[j * 2 + 0] + bb);
            v.y = gelu_exact(acc2[j * 2 + 1] + bb);
            *(float2*)(s_h2T + o * 16 + a2) = v;
        }
    }
    __syncthreads();

    // MLP layer 3: out = h2 @ W3 + b3, 128 -> 130
    {
        const int o4 = (tid & 31) * 4 + 2;
        const int a2 = (tid >> 5) * 2;
        float acc3[8];
        #pragma unroll
        for (int i = 0; i < 8; i++) acc3[i] = 0.f;
        #pragma unroll 4
        for (int k = 0; k < 128; k++) {
            const float* wp = W3 + k * 130 + o4;
            float2 wa = *(const float2*)(wp);
            float2 wb = *(const float2*)(wp + 2);
            float2 hh = *(const float2*)(s_h2T + k * 16 + a2);
            float wv[4] = {wa.x, wa.y, wb.x, wb.y};
            float hv[2] = {hh.x, hh.y};
            #pragma unroll
            for (int j = 0; j < 4; j++)
                #pragma unroll
                for (int m = 0; m < 2; m++)
                    acc3[j * 2 + m] += wv[j] * hv[m];
        }
        #pragma unroll
        for (int m = 0; m < 2; m++) {
            int n = n0 + a2 + m;
            float4 v;
            v.x = acc3[0 * 2 + m] + b3[o4 + 0];
            v.y = acc3[1 * 2 + m] + b3[o4 + 1];
            v.z = acc3[2 * 2 + m] + b3[o4 + 2];
            v.w = acc3[3 * 2 + m] + b3[o4 + 3];
            *(float4*)(out + (size_t)n * 128 + (o4 - 2)) = v;
        }

        if (tid < 32) {
            int atom = tid >> 1, col = tid & 1;
            float s = 0.f;
            #pragma unroll 4
            for (int k = 0; k < 128; k++)
                s += s_h2T[k * 16 + atom] * W3[k * 130 + col];
            s += b3[col];
            out[(size_t)N_ATOMS * 128 + (size_t)col * N_ATOMS + (n0 + atom)] = s;
        }
    }
}

extern "C" void kernel_launch(void* const* d_in, const int* in_sizes, int n_in,
                              void* d_out, int out_size, void* d_ws, size_t ws_size,
                              hipStream_t stream)
{
    const float* emb  = (const float*)d_in[0];
    const float* qch  = (const float*)d_in[1];
    const int*   pidx = (const int*)d_in[2];
    const float* gs   = (const float*)d_in[3];
    const float* gv   = (const float*)d_in[4];
    const float* agh  = (const float*)d_in[5];
    const float* W_gf = (const float*)d_in[6];
    const float* W1   = (const float*)d_in[7];
    const float* b1   = (const float*)d_in[8];
    const float* W2   = (const float*)d_in[9];
    const float* b2   = (const float*)d_in[10];
    const float* W3   = (const float*)d_in[11];
    const float* b3   = (const float*)d_in[12];
    const int*   idx_j = pidx + P_PAIRS;

    // workspace layout
    float* acc      = (float*)d_ws;                       // N*64 floats (12.8 MB)
    int*   counts   = (int*)(acc + (size_t)N_ATOMS * 64); // N ints
    int*   seg_off  = counts + N_ATOMS;                   // N+1 ints
    int*   cursor   = seg_off + N_ATOMS + 1;              // N ints
    int*   sorted_p = cursor + N_ATOMS;                   // P ints (6.4 MB)

    hipMemsetAsync(counts, 0, (size_t)N_ATOMS * sizeof(int), stream);

    hist_kernel<<<(P_PAIRS + 255) / 256, 256, 0, stream>>>(idx_j, counts);
    scan_kernel<<<1, SCAN_THREADS, 0, stream>>>(counts, seg_off, cursor);
    scatter_idx_kernel<<<(P_PAIRS + 255) / 256, 256, 0, stream>>>(idx_j, cursor, sorted_p);
    reduce_kernel<<<(N_ATOMS + 3) / 4, 256, 0, stream>>>(seg_off, sorted_p, gs, gv, acc);

    fused_atom_kernel<<<N_ATOMS / TA, 256, 0, stream>>>(
        emb, qch, acc, agh, W_gf, W1, b1, W2, b2, W3, b3, (float*)d_out);
}